// Round 3
// baseline (665.079 us; speedup 1.0000x reference)
//
#include <hip/hip_runtime.h>
#include <math.h>

typedef unsigned short u16;
typedef __bf16 bf16x8 __attribute__((ext_vector_type(8)));
typedef float f32x4 __attribute__((ext_vector_type(4)));

__device__ __forceinline__ u16 f2bf(float f) {
    unsigned u = __builtin_bit_cast(unsigned, f);
    u += 0x7FFFu + ((u >> 16) & 1u);
    return (u16)(u >> 16);
}
__device__ __forceinline__ float bf2f(u16 h) {
    return __builtin_bit_cast(float, ((unsigned)h) << 16);
}

#define GLOAD_LDS16(g, l)                                                     \
    __builtin_amdgcn_global_load_lds(                                         \
        (const __attribute__((address_space(1))) void*)(g),                   \
        (__attribute__((address_space(3))) void*)(l), 16, 0, 0)

// ---------------------------------------------------------------- converts
__global__ __launch_bounds__(256) void k_convert(const float* __restrict__ in,
                                                 u16* __restrict__ out, int n4) {
    int i = blockIdx.x * 256 + threadIdx.x;
    if (i >= n4) return;
    float4 v = ((const float4*)in)[i];
    union { u16 a[4]; unsigned long long q; } o;
    o.a[0] = f2bf(v.x); o.a[1] = f2bf(v.y); o.a[2] = f2bf(v.z); o.a[3] = f2bf(v.w);
    ((unsigned long long*)out)[i] = o.q;
}

// out[(c)*ldOut + colOff + r] = bf16(in[r*C + c]);  grid = (C/32, R/32)
__global__ __launch_bounds__(256) void k_transpose(const float* __restrict__ in, int R, int C,
                                                   u16* __restrict__ out, int ldOut, int colOff) {
    __shared__ float tile[32][33];
    int tr0 = blockIdx.y * 32;
    int tc0 = blockIdx.x * 32;
    int lr = threadIdx.x >> 5;   // 0..7
    int lc = threadIdx.x & 31;
#pragma unroll
    for (int i = 0; i < 4; i++) {
        int rr = lr + i * 8;
        tile[rr][lc] = in[(size_t)(tr0 + rr) * C + tc0 + lc];
    }
    __syncthreads();
#pragma unroll
    for (int i = 0; i < 4; i++) {
        int rr = lr + i * 8;
        out[(size_t)(tc0 + rr) * ldOut + colOff + tr0 + lc] = f2bf(tile[lc][rr]);
    }
}

// Wsym[u*S+v, :] = bf16(w[u*S+v, :] + w[v*S+u, :]); one block per (u,v), u<=v writes both
__global__ __launch_bounds__(256) void k_symmetrize(const float* __restrict__ w, int lg,
                                                    u16* __restrict__ out) {
    int j = blockIdx.x;
    int S = 1 << lg;
    int u = j >> lg, v = j & (S - 1);
    if (u > v) return;
    int jT = v * S + u;
    int c = threadIdx.x * 4;
    float4 a = *(const float4*)(w + (size_t)j * 1024 + c);
    float4 b = *(const float4*)(w + (size_t)jT * 1024 + c);
    union { u16 h[4]; unsigned long long q; } o;
    o.h[0] = f2bf(a.x + b.x); o.h[1] = f2bf(a.y + b.y);
    o.h[2] = f2bf(a.z + b.z); o.h[3] = f2bf(a.w + b.w);
    *(unsigned long long*)(out + (size_t)j * 1024 + c) = o.q;
    if (jT != j) *(unsigned long long*)(out + (size_t)jT * 1024 + c) = o.q;
}

// ---------------------------------------------------------------- features
__global__ __launch_bounds__(256) void k_features(const float* __restrict__ t,
                                                  u16* __restrict__ P) {
    __shared__ float tr[480];
    int b = blockIdx.x, tid = threadIdx.x;
    for (int i = tid; i < 480; i += 256) tr[i] = t[(size_t)b * 480 + i];
    __syncthreads();
    u16* row = P + (size_t)b * 21504;
    const float s1 = 0.57735026918962576f;
    const float s2 = 0.44721359549995794f;
    for (int k = tid; k < 16384; k += 256) {
        int u = k >> 7, v = k & 127;
        row[k] = f2bf(tr[u] * tr[v]);
    }
    const float* x1 = tr + 128;
    for (int k = tid; k < 4096; k += 256) {
        int u = k >> 6, v = k & 63;
        float s = x1[u*3+0]*x1[v*3+0] + x1[u*3+1]*x1[v*3+1] + x1[u*3+2]*x1[v*3+2];
        row[16384 + k] = f2bf(s * s1);
    }
    const float* x2 = tr + 320;
    for (int k = tid; k < 1024; k += 256) {
        int u = k >> 5, v = k & 31;
        float s = 0.f;
#pragma unroll
        for (int m = 0; m < 5; m++) s += x2[u*5+m] * x2[v*5+m];
        row[20480 + k] = f2bf(s * s2);
    }
}

// ---------------------------------------------------------------- GEMM (NT, BK=64)
// C[M,N] = scale*A[M,K]*B[N,K]^T + bias. 128x128x64 tile, 256 thr (2x2 waves).
// Two unpadded 128x32 LDS half-buffers per operand (keeps global_load_lds layout
// and m97 fragment-read pattern). gridDim.z>1 => fp32 partials (xIsM must be 0).
__global__ __launch_bounds__(256) void k_gemm2(const u16* __restrict__ A, int ldA,
                                               const u16* __restrict__ B, int ldB,
                                               int kLen, float scale,
                                               const float* __restrict__ bias,
                                               float* __restrict__ Cf,
                                               u16* __restrict__ Cb, int ldC,
                                               float* __restrict__ Cpart, int xIsM) {
    __shared__ u16 As[2][128 * 32];
    __shared__ u16 Bs[2][128 * 32];
    const int tid = threadIdx.x;
    const int wave = tid >> 6, lane = tid & 63;
    const int wm = wave >> 1, wn = wave & 1;
    const int bn = xIsM ? blockIdx.y : blockIdx.x;
    const int bm = xIsM ? blockIdx.x : blockIdx.y;
    const int m0 = bm * 128, n0 = bn * 128;
    const size_t kOff = (size_t)blockIdx.z * kLen;

    const u16* aG = A + (size_t)(m0 + wave * 32 + (lane >> 2)) * ldA + kOff + (lane & 3) * 8;
    const u16* bG = B + (size_t)(n0 + wave * 32 + (lane >> 2)) * ldB + kOff + (lane & 3) * 8;
    const size_t aS = (size_t)16 * ldA;
    const size_t bS = (size_t)16 * ldB;
    u16* aL0 = &As[0][(wave * 32) * 32];
    u16* aL1 = &As[0][(wave * 32 + 16) * 32];
    u16* aH0 = &As[1][(wave * 32) * 32];
    u16* aH1 = &As[1][(wave * 32 + 16) * 32];
    u16* bL0 = &Bs[0][(wave * 32) * 32];
    u16* bL1 = &Bs[0][(wave * 32 + 16) * 32];
    u16* bH0 = &Bs[1][(wave * 32) * 32];
    u16* bH1 = &Bs[1][(wave * 32 + 16) * 32];

    f32x4 acc[4][4];
#pragma unroll
    for (int i = 0; i < 4; i++)
#pragma unroll
        for (int j = 0; j < 4; j++) acc[i][j] = (f32x4){0.f, 0.f, 0.f, 0.f};

    const int ml = lane & 15, kq = (lane >> 4) * 8;
    const u16* aRd0 = &As[0][(wm * 64 + ml) * 32 + kq];
    const u16* bRd0 = &Bs[0][(wn * 64 + ml) * 32 + kq];
    const u16* aRd1 = &As[1][(wm * 64 + ml) * 32 + kq];
    const u16* bRd1 = &Bs[1][(wn * 64 + ml) * 32 + kq];

    for (int k = 0; k < kLen; k += 64) {
        GLOAD_LDS16(aG, aL0);
        GLOAD_LDS16(aG + aS, aL1);
        GLOAD_LDS16(aG + 32, aH0);
        GLOAD_LDS16(aG + aS + 32, aH1);
        GLOAD_LDS16(bG, bL0);
        GLOAD_LDS16(bG + bS, bL1);
        GLOAD_LDS16(bG + 32, bH0);
        GLOAD_LDS16(bG + bS + 32, bH1);
        aG += 64; bG += 64;
        __syncthreads();
        {
            bf16x8 af[4], bfv[4];
#pragma unroll
            for (int i = 0; i < 4; i++) af[i]  = *(const bf16x8*)(aRd0 + i * 16 * 32);
#pragma unroll
            for (int j = 0; j < 4; j++) bfv[j] = *(const bf16x8*)(bRd0 + j * 16 * 32);
#pragma unroll
            for (int i = 0; i < 4; i++)
#pragma unroll
                for (int j = 0; j < 4; j++)
                    acc[i][j] = __builtin_amdgcn_mfma_f32_16x16x32_bf16(af[i], bfv[j], acc[i][j], 0, 0, 0);
        }
        {
            bf16x8 af[4], bfv[4];
#pragma unroll
            for (int i = 0; i < 4; i++) af[i]  = *(const bf16x8*)(aRd1 + i * 16 * 32);
#pragma unroll
            for (int j = 0; j < 4; j++) bfv[j] = *(const bf16x8*)(bRd1 + j * 16 * 32);
#pragma unroll
            for (int i = 0; i < 4; i++)
#pragma unroll
                for (int j = 0; j < 4; j++)
                    acc[i][j] = __builtin_amdgcn_mfma_f32_16x16x32_bf16(af[i], bfv[j], acc[i][j], 0, 0, 0);
        }
        __syncthreads();
    }

    const int q = lane >> 4, nl = lane & 15;   // C/D: col=lane&15, row=(lane>>4)*4+reg
    if (gridDim.z > 1) {
        float* outP = Cpart + (size_t)blockIdx.z * ((size_t)gridDim.y * 128) * ldC;
#pragma unroll
        for (int i = 0; i < 4; i++)
#pragma unroll
            for (int j = 0; j < 4; j++)
#pragma unroll
                for (int reg = 0; reg < 4; reg++) {
                    int row = m0 + wm * 64 + i * 16 + q * 4 + reg;
                    int col = n0 + wn * 64 + j * 16 + nl;
                    outP[(size_t)row * ldC + col] = acc[i][j][reg];
                }
    } else {
#pragma unroll
        for (int i = 0; i < 4; i++)
#pragma unroll
            for (int j = 0; j < 4; j++)
#pragma unroll
                for (int reg = 0; reg < 4; reg++) {
                    int row = m0 + wm * 64 + i * 16 + q * 4 + reg;
                    int col = n0 + wn * 64 + j * 16 + nl;
                    float v = acc[i][j][reg] * scale + (bias ? bias[col] : 0.0f);
                    if (Cf) Cf[(size_t)row * ldC + col] = v;
                    else    Cb[(size_t)row * ldC + col] = f2bf(v);
                }
    }
}

// sum split-K partials + epilogue
__global__ __launch_bounds__(256) void k_reduce(const float* __restrict__ part, size_t stride,
                                                int SK, int total, int N, float scale,
                                                const float* __restrict__ bias,
                                                float* __restrict__ outF, u16* __restrict__ outB) {
    int i = blockIdx.x * 256 + threadIdx.x;
    if (i >= total) return;
    float s = 0.f;
    for (int z = 0; z < SK; z++) s += part[(size_t)z * stride + i];
    float v = s * scale + (bias ? bias[i % N] : 0.0f);
    if (outF) outF[i] = v;
    else      outB[i] = f2bf(v);
}

// ---------------------------------------------------------------- rowwise LN
__device__ __forceinline__ float blockReduce(float v, float* red) {
#pragma unroll
    for (int off = 32; off > 0; off >>= 1) v += __shfl_down(v, off);
    __syncthreads();
    if ((threadIdx.x & 63) == 0) red[threadIdx.x >> 6] = v;
    __syncthreads();
    return red[0] + red[1] + red[2] + red[3];
}

__global__ __launch_bounds__(256) void k_ln_fwd(const float* __restrict__ X, int D,
    const float* __restrict__ g, const float* __restrict__ be,
    float* __restrict__ mu_out, float* __restrict__ r_out,
    u16* __restrict__ a_bf, float* __restrict__ a_f32) {
    __shared__ float red[4];
    int b = blockIdx.x, tid = threadIdx.x;
    const float* x = X + (size_t)b * D;
    int nd = D >> 8;
    float s = 0.f, s2 = 0.f;
    for (int r = 0; r < nd; r++) { float v = x[tid + (r << 8)]; s += v; s2 += v * v; }
    s = blockReduce(s, red);
    s2 = blockReduce(s2, red);
    float mu = s / D;
    float var = s2 / D - mu * mu;
    float rst = rsqrtf(var + 1e-6f);
    if (tid == 0) { mu_out[b] = mu; r_out[b] = rst; }
    for (int r = 0; r < nd; r++) {
        int i = tid + (r << 8);
        float xh = (x[i] - mu) * rst;
        float ln = xh * g[i] + be[i];
        float a = ln / (1.0f + expf(-ln));
        if (a_bf)  a_bf[(size_t)b * D + i] = f2bf(a);
        if (a_f32) a_f32[(size_t)b * D + i] = a;
    }
}

__global__ __launch_bounds__(256) void k_ln_bwd(const float* __restrict__ dup,
    const float* __restrict__ X, const float* __restrict__ mu_in, const float* __restrict__ r_in,
    const float* __restrict__ g, const float* __restrict__ be,
    u16* __restrict__ out_bf, int D) {
    __shared__ float red[4];
    int b = blockIdx.x, tid = threadIdx.x;
    const float* x = X + (size_t)b * D;
    float mu = mu_in[b], rst = r_in[b];
    int nd = D >> 8;
    float w_[4], xh_[4];
    float sw = 0.f, swx = 0.f;
    for (int r = 0; r < nd; r++) {
        int i = tid + (r << 8);
        float xh = (x[i] - mu) * rst;
        float ln = xh * g[i] + be[i];
        float sg = 1.0f / (1.0f + expf(-ln));
        float dsilu = sg * (1.0f + ln * (1.0f - sg));
        float d = dup ? dup[(size_t)b * D + i] : 1.0f;
        float w = g[i] * dsilu * d;
        w_[r] = w; xh_[r] = xh;
        sw += w; swx += w * xh;
    }
    sw = blockReduce(sw, red);
    swx = blockReduce(swx, red);
    float invD = 1.0f / D;
    for (int r = 0; r < nd; r++) {
        int i = tid + (r << 8);
        float dx = rst * (w_[r] - sw * invD - xh_[r] * swx * invD);
        out_bf[(size_t)b * D + i] = f2bf(dx);
    }
}

// ---------------------------------------------------------------- contraction
// y[b,:] from SYMMETRIC Gsym (bf16, 21504) and t[b,:]: row dots only.
__global__ __launch_bounds__(256) void k_contract2(const u16* __restrict__ G,
                                                   const float* __restrict__ t,
                                                   float* __restrict__ y) {
    __shared__ float xs[480];
    __shared__ u16 gs[21504];
    int b = blockIdx.x, tid = threadIdx.x;
    for (int i = tid; i < 480; i += 256) xs[i] = t[(size_t)b * 480 + i];
    const uint4* src = (const uint4*)(G + (size_t)b * 21504);
    uint4* dst = (uint4*)gs;
    for (int i = tid; i < 2688; i += 256) dst[i] = src[i];
    __syncthreads();
    int wave = tid >> 6, lane = tid & 63;
    float* yr = y + (size_t)b * 480;
    const float s1 = 0.57735026918962576f;
    const float s2 = 0.44721359549995794f;
    // seg0: 128 u, wave handles 32
    for (int r = 0; r < 32; r++) {
        int u = wave * 32 + r;
        unsigned pk = *(const unsigned*)&gs[u * 128 + lane * 2];
        float acc = bf2f((u16)(pk & 0xffff)) * xs[lane * 2]
                  + bf2f((u16)(pk >> 16)) * xs[lane * 2 + 1];
#pragma unroll
        for (int off = 32; off > 0; off >>= 1) acc += __shfl_down(acc, off);
        if (lane == 0) yr[u] = acc;
    }
    // seg1: 64 u x 3 m, wave handles 16 u; lane = v (64 lanes = 64 v)
    {
        const u16* g1 = gs + 16384;
        for (int r = 0; r < 16; r++) {
            int u = wave * 16 + r;
            float gv = bf2f(g1[u * 64 + lane]);
            float a0 = gv * xs[128 + lane * 3 + 0];
            float a1 = gv * xs[128 + lane * 3 + 1];
            float a2 = gv * xs[128 + lane * 3 + 2];
#pragma unroll
            for (int off = 32; off > 0; off >>= 1) {
                a0 += __shfl_down(a0, off);
                a1 += __shfl_down(a1, off);
                a2 += __shfl_down(a2, off);
            }
            if (lane == 0) {
                yr[128 + u * 3 + 0] = a0 * s1;
                yr[128 + u * 3 + 1] = a1 * s1;
                yr[128 + u * 3 + 2] = a2 * s1;
            }
        }
    }
    // seg2: 32 u x 5 m, wave handles 8 u; lanes 0..31 = v
    {
        const u16* g2 = gs + 20480;
        for (int r = 0; r < 8; r++) {
            int u = wave * 8 + r;
            bool act = lane < 32;
            float gv = act ? bf2f(g2[u * 32 + lane]) : 0.f;
            float a[5];
#pragma unroll
            for (int m = 0; m < 5; m++)
                a[m] = act ? gv * xs[320 + lane * 5 + m] : 0.f;
#pragma unroll
            for (int off = 32; off > 0; off >>= 1)
#pragma unroll
                for (int m = 0; m < 5; m++) a[m] += __shfl_down(a[m], off);
            if (lane == 0)
#pragma unroll
                for (int m = 0; m < 5; m++) yr[320 + u * 5 + m] = a[m] * s2;
        }
    }
}

// ---------------------------------------------------------------- launch
extern "C" void kernel_launch(void* const* d_in, const int* in_sizes, int n_in,
                              void* d_out, int out_size, void* d_ws, size_t ws_size,
                              hipStream_t stream) {
    const float* t   = (const float*)d_in[0];
    const float* w0  = (const float*)d_in[1];
    const float* w1  = (const float*)d_in[2];
    const float* w2  = (const float*)d_in[3];
    const float* W1  = (const float*)d_in[4];
    const float* b1  = (const float*)d_in[5];
    const float* g1  = (const float*)d_in[6];
    const float* be1 = (const float*)d_in[7];
    const float* W2  = (const float*)d_in[8];
    const float* b2  = (const float*)d_in[9];
    const float* g2  = (const float*)d_in[10];
    const float* be2 = (const float*)d_in[11];

    float* xout = (float*)d_out;                    // 2048*256
    float* yout = xout + (size_t)2048 * 256;        // 2048*480

    char* ws = (char*)d_ws;
    size_t off = 0;
    auto alloc = [&](size_t bytes) -> void* {
        void* p = ws + off;
        off += (bytes + 255) & ~(size_t)255;
        return p;
    };
    u16*   PG    = (u16*)alloc((size_t)2048 * 21504 * 2);  // P, later Gsym (aliased)
    u16*   Wtb   = (u16*)alloc((size_t)1024 * 21504 * 2);  // W^T bf16; later Wsym (aliased)
    u16*   W1b   = (u16*)alloc((size_t)1024 * 1024 * 2);
    u16*   W1tb  = (u16*)alloc((size_t)1024 * 1024 * 2);
    u16*   W2b   = (u16*)alloc((size_t)1024 * 256 * 2);
    u16*   W2tb  = (u16*)alloc((size_t)256 * 1024 * 2);
    u16*   h_bf  = (u16*)alloc((size_t)2048 * 1024 * 2);
    float* h1pre = (float*)alloc((size_t)2048 * 1024 * 4);
    float* mu1   = (float*)alloc(2048 * 4);
    float* r1    = (float*)alloc(2048 * 4);
    u16*   a1_bf = (u16*)alloc((size_t)2048 * 1024 * 2);
    float* h2pre = (float*)alloc((size_t)2048 * 256 * 4);
    float* mu2   = (float*)alloc(2048 * 4);
    float* r2    = (float*)alloc(2048 * 4);
    u16*   dh2b  = (u16*)alloc((size_t)2048 * 256 * 2);
    float* d_a1  = (float*)alloc((size_t)2048 * 1024 * 4);
    u16*   dh1b  = (u16*)alloc((size_t)2048 * 1024 * 2);
    u16*   de_bf = (u16*)alloc((size_t)2048 * 1024 * 2);
    float* Cpart = (float*)(ws + off);
    size_t cpartBytes = (ws_size > off) ? (ws_size - off) : 0;
    (void)in_sizes; (void)n_in; (void)out_size;

    const float sF = 1.0f / sqrtf(21504.0f);

    // GEMM helper: N,M multiples of 128; ldC == N; K/SK must be a multiple of 64
    auto gemm = [&](const u16* A, int ldA, const u16* B, int ldB, int M, int N, int K,
                    int SKwant, float scale, const float* bias,
                    float* Cf, u16* Cb, int ldC, int xIsM) {
        int SK = xIsM ? 1 : SKwant;
        size_t slice = (size_t)M * ldC * 4;
        if (SK > 1 && cpartBytes < 2 * slice) SK = 1;
        if (SK > 1 && (size_t)SK * slice > cpartBytes) SK = (int)(cpartBytes / slice);
        while (SK > 1 && !((K % SK) == 0 && ((K / SK) % 64) == 0)) SK--;
        dim3 grid(xIsM ? M / 128 : N / 128, xIsM ? N / 128 : M / 128, SK);
        if (SK > 1) {
            k_gemm2<<<grid, 256, 0, stream>>>(A, ldA, B, ldB, K / SK, 0.f, nullptr,
                                              nullptr, nullptr, ldC, Cpart, 0);
            int total = M * ldC;
            k_reduce<<<(total + 255) / 256, 256, 0, stream>>>(Cpart, (size_t)M * ldC, SK,
                                                              total, N, scale, bias, Cf, Cb);
        } else {
            k_gemm2<<<grid, 256, 0, stream>>>(A, ldA, B, ldB, K, scale, bias,
                                              Cf, Cb, ldC, nullptr, xIsM);
        }
    };

    // weight prep (W^T layouts for forward GEMMs)
    k_transpose<<<dim3(32, 512), 256, 0, stream>>>(w0, 16384, 1024, Wtb, 21504, 0);
    k_transpose<<<dim3(32, 128), 256, 0, stream>>>(w1, 4096, 1024, Wtb, 21504, 16384);
    k_transpose<<<dim3(32, 32),  256, 0, stream>>>(w2, 1024, 1024, Wtb, 21504, 20480);
    k_transpose<<<dim3(32, 32),  256, 0, stream>>>(W1, 1024, 1024, W1tb, 1024, 0);
    k_transpose<<<dim3(8, 32),   256, 0, stream>>>(W2, 1024, 256, W2tb, 1024, 0);
    k_convert<<<1024 * 1024 / 1024, 256, 0, stream>>>(W1, W1b, 1024 * 1024 / 4);
    k_convert<<<1024 * 256 / 1024, 256, 0, stream>>>(W2, W2b, 1024 * 256 / 4);

    // features -> P
    k_features<<<2048, 256, 0, stream>>>(t, PG);

    // h = sF * P @ Wt^T  (bf16 out), split-K for occupancy
    gemm(PG, 21504, Wtb, 21504, 2048, 1024, 21504, 8, sF, nullptr, nullptr, h_bf, 1024, 0);

    // Wtb dead -> overwrite with symmetrized straight-layout Wsym (for Gsym = de @ Wsym)
    u16* Wsymb = Wtb;
    k_symmetrize<<<16384, 256, 0, stream>>>(w0, 7, Wsymb);
    k_symmetrize<<<4096, 256, 0, stream>>>(w1, 6, Wsymb + (size_t)16384 * 1024);
    k_symmetrize<<<1024, 256, 0, stream>>>(w2, 5, Wsymb + (size_t)20480 * 1024);

    // MLP forward
    gemm(h_bf, 1024, W1tb, 1024, 2048, 1024, 1024, 2, 1.0f, b1, h1pre, nullptr, 1024, 0);
    k_ln_fwd<<<2048, 256, 0, stream>>>(h1pre, 1024, g1, be1, mu1, r1, a1_bf, nullptr);
    gemm(a1_bf, 1024, W2tb, 1024, 2048, 256, 1024, 8, 1.0f, b2, h2pre, nullptr, 256, 0);
    k_ln_fwd<<<2048, 256, 0, stream>>>(h2pre, 256, g2, be2, mu2, r2, nullptr, xout);

    // backward
    k_ln_bwd<<<2048, 256, 0, stream>>>(nullptr, h2pre, mu2, r2, g2, be2, dh2b, 256);
    gemm(dh2b, 256, W2b, 256, 2048, 1024, 256, 2, 1.0f, nullptr, d_a1, nullptr, 1024, 0);
    k_ln_bwd<<<2048, 256, 0, stream>>>(d_a1, h1pre, mu1, r1, g1, be1, dh1b, 1024);
    gemm(dh1b, 1024, W1b, 1024, 2048, 1024, 1024, 2, sF, nullptr, nullptr, de_bf, 1024, 0);

    // Gsym = de @ Wsym (NT), bf16 out, aliases P; x-fastest = M-tiles for Wsym L2 reuse
    gemm(de_bf, 1024, Wsymb, 1024, 2048, 21504, 1024, 1, 1.0f, nullptr, nullptr, PG, 21504, 1);

    // y[b,:] = row-dots of symmetric Gsym with x per segment
    k_contract2<<<2048, 256, 0, stream>>>(PG, t, yout);
}

// Round 4
// 659.150 us; speedup vs baseline: 1.0090x; 1.0090x over previous
//
#include <hip/hip_runtime.h>
#include <math.h>

typedef unsigned short u16;
typedef __bf16 bf16x8 __attribute__((ext_vector_type(8)));
typedef float f32x4 __attribute__((ext_vector_type(4)));

__device__ __forceinline__ u16 f2bf(float f) {
    unsigned u = __builtin_bit_cast(unsigned, f);
    u += 0x7FFFu + ((u >> 16) & 1u);
    return (u16)(u >> 16);
}
__device__ __forceinline__ float bf2f(u16 h) {
    return __builtin_bit_cast(float, ((unsigned)h) << 16);
}

#define GLOAD_LDS16(g, l)                                                     \
    __builtin_amdgcn_global_load_lds(                                         \
        (const __attribute__((address_space(1))) void*)(g),                   \
        (__attribute__((address_space(3))) void*)(l), 16, 0, 0)

// ---------------------------------------------------------------- converts
__global__ __launch_bounds__(256) void k_convert(const float* __restrict__ in,
                                                 u16* __restrict__ out, int n4) {
    int i = blockIdx.x * 256 + threadIdx.x;
    if (i >= n4) return;
    float4 v = ((const float4*)in)[i];
    union { u16 a[4]; unsigned long long q; } o;
    o.a[0] = f2bf(v.x); o.a[1] = f2bf(v.y); o.a[2] = f2bf(v.z); o.a[3] = f2bf(v.w);
    ((unsigned long long*)out)[i] = o.q;
}

// out[(c)*ldOut + colOff + r] = bf16(in[r*C + c]);  grid = (C/32, R/32)
__global__ __launch_bounds__(256) void k_transpose(const float* __restrict__ in, int R, int C,
                                                   u16* __restrict__ out, int ldOut, int colOff) {
    __shared__ float tile[32][33];
    int tr0 = blockIdx.y * 32;
    int tc0 = blockIdx.x * 32;
    int lr = threadIdx.x >> 5;   // 0..7
    int lc = threadIdx.x & 31;
#pragma unroll
    for (int i = 0; i < 4; i++) {
        int rr = lr + i * 8;
        tile[rr][lc] = in[(size_t)(tr0 + rr) * C + tc0 + lc];
    }
    __syncthreads();
#pragma unroll
    for (int i = 0; i < 4; i++) {
        int rr = lr + i * 8;
        out[(size_t)(tc0 + rr) * ldOut + colOff + tr0 + lc] = f2bf(tile[lc][rr]);
    }
}

// Wsym[u*S+v, :] = bf16(w[u*S+v, :] + w[v*S+u, :]); one block per (u,v), u<=v writes both
__global__ __launch_bounds__(256) void k_symmetrize(const float* __restrict__ w, int lg,
                                                    u16* __restrict__ out) {
    int j = blockIdx.x;
    int S = 1 << lg;
    int u = j >> lg, v = j & (S - 1);
    if (u > v) return;
    int jT = v * S + u;
    int c = threadIdx.x * 4;
    float4 a = *(const float4*)(w + (size_t)j * 1024 + c);
    float4 b = *(const float4*)(w + (size_t)jT * 1024 + c);
    union { u16 h[4]; unsigned long long q; } o;
    o.h[0] = f2bf(a.x + b.x); o.h[1] = f2bf(a.y + b.y);
    o.h[2] = f2bf(a.z + b.z); o.h[3] = f2bf(a.w + b.w);
    *(unsigned long long*)(out + (size_t)j * 1024 + c) = o.q;
    if (jT != j) *(unsigned long long*)(out + (size_t)jT * 1024 + c) = o.q;
}

// ---------------------------------------------------------------- features
__global__ __launch_bounds__(256) void k_features(const float* __restrict__ t,
                                                  u16* __restrict__ P) {
    __shared__ float tr[480];
    int b = blockIdx.x, tid = threadIdx.x;
    for (int i = tid; i < 480; i += 256) tr[i] = t[(size_t)b * 480 + i];
    __syncthreads();
    u16* row = P + (size_t)b * 21504;
    const float s1 = 0.57735026918962576f;
    const float s2 = 0.44721359549995794f;
    for (int k = tid; k < 16384; k += 256) {
        int u = k >> 7, v = k & 127;
        row[k] = f2bf(tr[u] * tr[v]);
    }
    const float* x1 = tr + 128;
    for (int k = tid; k < 4096; k += 256) {
        int u = k >> 6, v = k & 63;
        float s = x1[u*3+0]*x1[v*3+0] + x1[u*3+1]*x1[v*3+1] + x1[u*3+2]*x1[v*3+2];
        row[16384 + k] = f2bf(s * s1);
    }
    const float* x2 = tr + 320;
    for (int k = tid; k < 1024; k += 256) {
        int u = k >> 5, v = k & 31;
        float s = 0.f;
#pragma unroll
        for (int m = 0; m < 5; m++) s += x2[u*5+m] * x2[v*5+m];
        row[20480 + k] = f2bf(s * s2);
    }
}

// ---------------------------------------------------------------- GEMM (NT, BK=64)
__global__ __launch_bounds__(256) void k_gemm2(const u16* __restrict__ A, int ldA,
                                               const u16* __restrict__ B, int ldB,
                                               int kLen, float scale,
                                               const float* __restrict__ bias,
                                               float* __restrict__ Cf,
                                               u16* __restrict__ Cb, int ldC,
                                               float* __restrict__ Cpart) {
    __shared__ u16 As[2][128 * 32];
    __shared__ u16 Bs[2][128 * 32];
    const int tid = threadIdx.x;
    const int wave = tid >> 6, lane = tid & 63;
    const int wm = wave >> 1, wn = wave & 1;
    const int m0 = blockIdx.y * 128, n0 = blockIdx.x * 128;
    const size_t kOff = (size_t)blockIdx.z * kLen;

    const u16* aG = A + (size_t)(m0 + wave * 32 + (lane >> 2)) * ldA + kOff + (lane & 3) * 8;
    const u16* bG = B + (size_t)(n0 + wave * 32 + (lane >> 2)) * ldB + kOff + (lane & 3) * 8;
    const size_t aS = (size_t)16 * ldA;
    const size_t bS = (size_t)16 * ldB;
    u16* aL0 = &As[0][(wave * 32) * 32];
    u16* aL1 = &As[0][(wave * 32 + 16) * 32];
    u16* aH0 = &As[1][(wave * 32) * 32];
    u16* aH1 = &As[1][(wave * 32 + 16) * 32];
    u16* bL0 = &Bs[0][(wave * 32) * 32];
    u16* bL1 = &Bs[0][(wave * 32 + 16) * 32];
    u16* bH0 = &Bs[1][(wave * 32) * 32];
    u16* bH1 = &Bs[1][(wave * 32 + 16) * 32];

    f32x4 acc[4][4];
#pragma unroll
    for (int i = 0; i < 4; i++)
#pragma unroll
        for (int j = 0; j < 4; j++) acc[i][j] = (f32x4){0.f, 0.f, 0.f, 0.f};

    const int ml = lane & 15, kq = (lane >> 4) * 8;
    const u16* aRd0 = &As[0][(wm * 64 + ml) * 32 + kq];
    const u16* bRd0 = &Bs[0][(wn * 64 + ml) * 32 + kq];
    const u16* aRd1 = &As[1][(wm * 64 + ml) * 32 + kq];
    const u16* bRd1 = &Bs[1][(wn * 64 + ml) * 32 + kq];

    for (int k = 0; k < kLen; k += 64) {
        GLOAD_LDS16(aG, aL0);
        GLOAD_LDS16(aG + aS, aL1);
        GLOAD_LDS16(aG + 32, aH0);
        GLOAD_LDS16(aG + aS + 32, aH1);
        GLOAD_LDS16(bG, bL0);
        GLOAD_LDS16(bG + bS, bL1);
        GLOAD_LDS16(bG + 32, bH0);
        GLOAD_LDS16(bG + bS + 32, bH1);
        aG += 64; bG += 64;
        __syncthreads();
        {
            bf16x8 af[4], bfv[4];
#pragma unroll
            for (int i = 0; i < 4; i++) af[i]  = *(const bf16x8*)(aRd0 + i * 16 * 32);
#pragma unroll
            for (int j = 0; j < 4; j++) bfv[j] = *(const bf16x8*)(bRd0 + j * 16 * 32);
#pragma unroll
            for (int i = 0; i < 4; i++)
#pragma unroll
                for (int j = 0; j < 4; j++)
                    acc[i][j] = __builtin_amdgcn_mfma_f32_16x16x32_bf16(af[i], bfv[j], acc[i][j], 0, 0, 0);
        }
        {
            bf16x8 af[4], bfv[4];
#pragma unroll
            for (int i = 0; i < 4; i++) af[i]  = *(const bf16x8*)(aRd1 + i * 16 * 32);
#pragma unroll
            for (int j = 0; j < 4; j++) bfv[j] = *(const bf16x8*)(bRd1 + j * 16 * 32);
#pragma unroll
            for (int i = 0; i < 4; i++)
#pragma unroll
                for (int j = 0; j < 4; j++)
                    acc[i][j] = __builtin_amdgcn_mfma_f32_16x16x32_bf16(af[i], bfv[j], acc[i][j], 0, 0, 0);
        }
        __syncthreads();
    }

    const int q = lane >> 4, nl = lane & 15;   // C/D: col=lane&15, row=(lane>>4)*4+reg
    if (gridDim.z > 1) {
        float* outP = Cpart + (size_t)blockIdx.z * ((size_t)gridDim.y * 128) * ldC;
#pragma unroll
        for (int i = 0; i < 4; i++)
#pragma unroll
            for (int j = 0; j < 4; j++)
#pragma unroll
                for (int reg = 0; reg < 4; reg++) {
                    int row = m0 + wm * 64 + i * 16 + q * 4 + reg;
                    int col = n0 + wn * 64 + j * 16 + nl;
                    outP[(size_t)row * ldC + col] = acc[i][j][reg];
                }
    } else {
#pragma unroll
        for (int i = 0; i < 4; i++)
#pragma unroll
            for (int j = 0; j < 4; j++)
#pragma unroll
                for (int reg = 0; reg < 4; reg++) {
                    int row = m0 + wm * 64 + i * 16 + q * 4 + reg;
                    int col = n0 + wn * 64 + j * 16 + nl;
                    float v = acc[i][j][reg] * scale + (bias ? bias[col] : 0.0f);
                    if (Cf) Cf[(size_t)row * ldC + col] = v;
                    else    Cb[(size_t)row * ldC + col] = f2bf(v);
                }
    }
}

// ---------------------------------------------------------------- GEMM_G (fused)
// Gsym-tile = de[M,K] @ Wsym[N,K]^T.  bn<128 (seg0): fuse y0[b,bn]=sum_v tile*x0[b,v],
// write only y (4 B/row).  bn>=128: write bf16 tail tile to Gt (ld 5120).
__global__ __launch_bounds__(256) void k_gemmG(const u16* __restrict__ A, int ldA,
                                               const u16* __restrict__ B, int ldB,
                                               int kLen,
                                               const float* __restrict__ t,
                                               float* __restrict__ y,
                                               u16* __restrict__ Gt) {
    __shared__ u16 As[2][128 * 32];
    __shared__ u16 Bs[2][128 * 32];
    __shared__ float part[2][128];
    const int tid = threadIdx.x;
    const int wave = tid >> 6, lane = tid & 63;
    const int wm = wave >> 1, wn = wave & 1;
    const int bm = blockIdx.x, bn = blockIdx.y;   // x fastest = M-tiles share B-tile
    const int m0 = bm * 128, n0 = bn * 128;

    const u16* aG = A + (size_t)(m0 + wave * 32 + (lane >> 2)) * ldA + (lane & 3) * 8;
    const u16* bG = B + (size_t)(n0 + wave * 32 + (lane >> 2)) * ldB + (lane & 3) * 8;
    const size_t aS = (size_t)16 * ldA;
    const size_t bS = (size_t)16 * ldB;
    u16* aL0 = &As[0][(wave * 32) * 32];
    u16* aL1 = &As[0][(wave * 32 + 16) * 32];
    u16* aH0 = &As[1][(wave * 32) * 32];
    u16* aH1 = &As[1][(wave * 32 + 16) * 32];
    u16* bL0 = &Bs[0][(wave * 32) * 32];
    u16* bL1 = &Bs[0][(wave * 32 + 16) * 32];
    u16* bH0 = &Bs[1][(wave * 32) * 32];
    u16* bH1 = &Bs[1][(wave * 32 + 16) * 32];

    f32x4 acc[4][4];
#pragma unroll
    for (int i = 0; i < 4; i++)
#pragma unroll
        for (int j = 0; j < 4; j++) acc[i][j] = (f32x4){0.f, 0.f, 0.f, 0.f};

    const int ml = lane & 15, kq = (lane >> 4) * 8;
    const u16* aRd0 = &As[0][(wm * 64 + ml) * 32 + kq];
    const u16* bRd0 = &Bs[0][(wn * 64 + ml) * 32 + kq];
    const u16* aRd1 = &As[1][(wm * 64 + ml) * 32 + kq];
    const u16* bRd1 = &Bs[1][(wn * 64 + ml) * 32 + kq];

    for (int k = 0; k < kLen; k += 64) {
        GLOAD_LDS16(aG, aL0);
        GLOAD_LDS16(aG + aS, aL1);
        GLOAD_LDS16(aG + 32, aH0);
        GLOAD_LDS16(aG + aS + 32, aH1);
        GLOAD_LDS16(bG, bL0);
        GLOAD_LDS16(bG + bS, bL1);
        GLOAD_LDS16(bG + 32, bH0);
        GLOAD_LDS16(bG + bS + 32, bH1);
        aG += 64; bG += 64;
        __syncthreads();
        {
            bf16x8 af[4], bfv[4];
#pragma unroll
            for (int i = 0; i < 4; i++) af[i]  = *(const bf16x8*)(aRd0 + i * 16 * 32);
#pragma unroll
            for (int j = 0; j < 4; j++) bfv[j] = *(const bf16x8*)(bRd0 + j * 16 * 32);
#pragma unroll
            for (int i = 0; i < 4; i++)
#pragma unroll
                for (int j = 0; j < 4; j++)
                    acc[i][j] = __builtin_amdgcn_mfma_f32_16x16x32_bf16(af[i], bfv[j], acc[i][j], 0, 0, 0);
        }
        {
            bf16x8 af[4], bfv[4];
#pragma unroll
            for (int i = 0; i < 4; i++) af[i]  = *(const bf16x8*)(aRd1 + i * 16 * 32);
#pragma unroll
            for (int j = 0; j < 4; j++) bfv[j] = *(const bf16x8*)(bRd1 + j * 16 * 32);
#pragma unroll
            for (int i = 0; i < 4; i++)
#pragma unroll
                for (int j = 0; j < 4; j++)
                    acc[i][j] = __builtin_amdgcn_mfma_f32_16x16x32_bf16(af[i], bfv[j], acc[i][j], 0, 0, 0);
        }
        __syncthreads();
    }

    const int q = lane >> 4, nl = lane & 15;
    if (bn < 128) {
        // fused contraction: y0[m0+row, bn] = sum over 128 cols of tile * t[row, v]
#pragma unroll
        for (int i = 0; i < 4; i++)
#pragma unroll
            for (int reg = 0; reg < 4; reg++) {
                int rowL = wm * 64 + i * 16 + q * 4 + reg;
                const float* xr = t + (size_t)(m0 + rowL) * 480 + wn * 64 + nl;
                float s = 0.f;
#pragma unroll
                for (int j = 0; j < 4; j++) s += acc[i][j][reg] * xr[j * 16];
                s += __shfl_xor(s, 1);
                s += __shfl_xor(s, 2);
                s += __shfl_xor(s, 4);
                s += __shfl_xor(s, 8);
                if (nl == 0) part[wn][rowL] = s;
            }
        __syncthreads();
        if (tid < 128) y[(size_t)(m0 + tid) * 480 + bn] = part[0][tid] + part[1][tid];
    } else {
        int c0 = (bn - 128) * 128;
#pragma unroll
        for (int i = 0; i < 4; i++)
#pragma unroll
            for (int j = 0; j < 4; j++)
#pragma unroll
                for (int reg = 0; reg < 4; reg++) {
                    int row = m0 + wm * 64 + i * 16 + q * 4 + reg;
                    int col = c0 + wn * 64 + j * 16 + nl;
                    Gt[(size_t)row * 5120 + col] = f2bf(acc[i][j][reg]);
                }
    }
}

// sum split-K partials + epilogue
__global__ __launch_bounds__(256) void k_reduce(const float* __restrict__ part, size_t stride,
                                                int SK, int total, int N, float scale,
                                                const float* __restrict__ bias,
                                                float* __restrict__ outF, u16* __restrict__ outB) {
    int i = blockIdx.x * 256 + threadIdx.x;
    if (i >= total) return;
    float s = 0.f;
    for (int z = 0; z < SK; z++) s += part[(size_t)z * stride + i];
    float v = s * scale + (bias ? bias[i % N] : 0.0f);
    if (outF) outF[i] = v;
    else      outB[i] = f2bf(v);
}

// ---------------------------------------------------------------- rowwise LN
__device__ __forceinline__ float blockReduce(float v, float* red) {
#pragma unroll
    for (int off = 32; off > 0; off >>= 1) v += __shfl_down(v, off);
    __syncthreads();
    if ((threadIdx.x & 63) == 0) red[threadIdx.x >> 6] = v;
    __syncthreads();
    return red[0] + red[1] + red[2] + red[3];
}

__global__ __launch_bounds__(256) void k_ln_fwd(const float* __restrict__ X, int D,
    const float* __restrict__ g, const float* __restrict__ be,
    float* __restrict__ mu_out, float* __restrict__ r_out,
    u16* __restrict__ a_bf, float* __restrict__ a_f32) {
    __shared__ float red[4];
    int b = blockIdx.x, tid = threadIdx.x;
    const float* x = X + (size_t)b * D;
    int nd = D >> 8;
    float s = 0.f, s2 = 0.f;
    for (int r = 0; r < nd; r++) { float v = x[tid + (r << 8)]; s += v; s2 += v * v; }
    s = blockReduce(s, red);
    s2 = blockReduce(s2, red);
    float mu = s / D;
    float var = s2 / D - mu * mu;
    float rst = rsqrtf(var + 1e-6f);
    if (tid == 0) { mu_out[b] = mu; r_out[b] = rst; }
    for (int r = 0; r < nd; r++) {
        int i = tid + (r << 8);
        float xh = (x[i] - mu) * rst;
        float ln = xh * g[i] + be[i];
        float a = ln / (1.0f + expf(-ln));
        if (a_bf)  a_bf[(size_t)b * D + i] = f2bf(a);
        if (a_f32) a_f32[(size_t)b * D + i] = a;
    }
}

__global__ __launch_bounds__(256) void k_ln_bwd(const float* __restrict__ dup,
    const float* __restrict__ X, const float* __restrict__ mu_in, const float* __restrict__ r_in,
    const float* __restrict__ g, const float* __restrict__ be,
    u16* __restrict__ out_bf, int D) {
    __shared__ float red[4];
    int b = blockIdx.x, tid = threadIdx.x;
    const float* x = X + (size_t)b * D;
    float mu = mu_in[b], rst = r_in[b];
    int nd = D >> 8;
    float w_[4], xh_[4];
    float sw = 0.f, swx = 0.f;
    for (int r = 0; r < nd; r++) {
        int i = tid + (r << 8);
        float xh = (x[i] - mu) * rst;
        float ln = xh * g[i] + be[i];
        float sg = 1.0f / (1.0f + expf(-ln));
        float dsilu = sg * (1.0f + ln * (1.0f - sg));
        float d = dup ? dup[(size_t)b * D + i] : 1.0f;
        float w = g[i] * dsilu * d;
        w_[r] = w; xh_[r] = xh;
        sw += w; swx += w * xh;
    }
    sw = blockReduce(sw, red);
    swx = blockReduce(swx, red);
    float invD = 1.0f / D;
    for (int r = 0; r < nd; r++) {
        int i = tid + (r << 8);
        float dx = rst * (w_[r] - sw * invD - xh_[r] * swx * invD);
        out_bf[(size_t)b * D + i] = f2bf(dx);
    }
}

// ---------------------------------------------------------------- tail contraction
// seg1/seg2 only, from Gt[2048][5120] (symmetric-weight grad tail)
__global__ __launch_bounds__(256) void k_contract_tail(const u16* __restrict__ Gt,
                                                       const float* __restrict__ t,
                                                       float* __restrict__ y) {
    __shared__ float xs[480];
    __shared__ u16 gs[5120];
    int b = blockIdx.x, tid = threadIdx.x;
    for (int i = tid; i < 480; i += 256) xs[i] = t[(size_t)b * 480 + i];
    const uint4* src = (const uint4*)(Gt + (size_t)b * 5120);
    uint4* dst = (uint4*)gs;
    for (int i = tid; i < 640; i += 256) dst[i] = src[i];
    __syncthreads();
    int wave = tid >> 6, lane = tid & 63;
    float* yr = y + (size_t)b * 480;
    const float s1 = 0.57735026918962576f;
    const float s2 = 0.44721359549995794f;
    // seg1: 64 u x 3 m; wave handles 16 u; lane = v
    for (int r = 0; r < 16; r++) {
        int u = wave * 16 + r;
        float gv = bf2f(gs[u * 64 + lane]);
        float a0 = gv * xs[128 + lane * 3 + 0];
        float a1 = gv * xs[128 + lane * 3 + 1];
        float a2 = gv * xs[128 + lane * 3 + 2];
#pragma unroll
        for (int off = 32; off > 0; off >>= 1) {
            a0 += __shfl_down(a0, off);
            a1 += __shfl_down(a1, off);
            a2 += __shfl_down(a2, off);
        }
        if (lane == 0) {
            yr[128 + u * 3 + 0] = a0 * s1;
            yr[128 + u * 3 + 1] = a1 * s1;
            yr[128 + u * 3 + 2] = a2 * s1;
        }
    }
    // seg2: 32 u x 5 m; wave handles 8 u; lanes 0..31 = v
    for (int r = 0; r < 8; r++) {
        int u = wave * 8 + r;
        bool act = lane < 32;
        float gv = act ? bf2f(gs[4096 + u * 32 + lane]) : 0.f;
        float a[5];
#pragma unroll
        for (int m = 0; m < 5; m++)
            a[m] = act ? gv * xs[320 + lane * 5 + m] : 0.f;
#pragma unroll
        for (int off = 32; off > 0; off >>= 1)
#pragma unroll
            for (int m = 0; m < 5; m++) a[m] += __shfl_down(a[m], off);
        if (lane == 0)
#pragma unroll
            for (int m = 0; m < 5; m++) yr[320 + u * 5 + m] = a[m] * s2;
    }
}

// ---------------------------------------------------------------- launch
extern "C" void kernel_launch(void* const* d_in, const int* in_sizes, int n_in,
                              void* d_out, int out_size, void* d_ws, size_t ws_size,
                              hipStream_t stream) {
    const float* t   = (const float*)d_in[0];
    const float* w0  = (const float*)d_in[1];
    const float* w1  = (const float*)d_in[2];
    const float* w2  = (const float*)d_in[3];
    const float* W1  = (const float*)d_in[4];
    const float* b1  = (const float*)d_in[5];
    const float* g1  = (const float*)d_in[6];
    const float* be1 = (const float*)d_in[7];
    const float* W2  = (const float*)d_in[8];
    const float* b2  = (const float*)d_in[9];
    const float* g2  = (const float*)d_in[10];
    const float* be2 = (const float*)d_in[11];

    float* xout = (float*)d_out;                    // 2048*256
    float* yout = xout + (size_t)2048 * 256;        // 2048*480

    char* ws = (char*)d_ws;
    size_t off = 0;
    auto alloc = [&](size_t bytes) -> void* {
        void* p = ws + off;
        off += (bytes + 255) & ~(size_t)255;
        return p;
    };
    u16*   PG    = (u16*)alloc((size_t)2048 * 21504 * 2);  // P, later Gt tail (aliased)
    u16*   Wtb   = (u16*)alloc((size_t)1024 * 21504 * 2);  // W^T bf16; later Wsym (aliased)
    u16*   W1b   = (u16*)alloc((size_t)1024 * 1024 * 2);
    u16*   W1tb  = (u16*)alloc((size_t)1024 * 1024 * 2);
    u16*   W2b   = (u16*)alloc((size_t)1024 * 256 * 2);
    u16*   W2tb  = (u16*)alloc((size_t)256 * 1024 * 2);
    u16*   h_bf  = (u16*)alloc((size_t)2048 * 1024 * 2);
    float* h1pre = (float*)alloc((size_t)2048 * 1024 * 4);
    float* mu1   = (float*)alloc(2048 * 4);
    float* r1    = (float*)alloc(2048 * 4);
    u16*   a1_bf = (u16*)alloc((size_t)2048 * 1024 * 2);
    float* h2pre = (float*)alloc((size_t)2048 * 256 * 4);
    float* mu2   = (float*)alloc(2048 * 4);
    float* r2    = (float*)alloc(2048 * 4);
    u16*   dh2b  = (u16*)alloc((size_t)2048 * 256 * 2);
    float* d_a1  = (float*)alloc((size_t)2048 * 1024 * 4);
    u16*   dh1b  = (u16*)alloc((size_t)2048 * 1024 * 2);
    u16*   de_bf = (u16*)alloc((size_t)2048 * 1024 * 2);
    float* Cpart = (float*)(ws + off);
    size_t cpartBytes = (ws_size > off) ? (ws_size - off) : 0;
    (void)in_sizes; (void)n_in; (void)out_size;

    const float sF = 1.0f / sqrtf(21504.0f);

    // GEMM helper: N,M multiples of 128; ldC == N; K/SK must be a multiple of 64
    auto gemm = [&](const u16* A, int ldA, const u16* B, int ldB, int M, int N, int K,
                    int SKwant, float scale, const float* bias,
                    float* Cf, u16* Cb, int ldC) {
        int SK = SKwant;
        size_t slice = (size_t)M * ldC * 4;
        if (SK > 1 && cpartBytes < 2 * slice) SK = 1;
        if (SK > 1 && (size_t)SK * slice > cpartBytes) SK = (int)(cpartBytes / slice);
        while (SK > 1 && !((K % SK) == 0 && ((K / SK) % 64) == 0)) SK--;
        dim3 grid(N / 128, M / 128, SK);
        if (SK > 1) {
            k_gemm2<<<grid, 256, 0, stream>>>(A, ldA, B, ldB, K / SK, 0.f, nullptr,
                                              nullptr, nullptr, ldC, Cpart);
            int total = M * ldC;
            k_reduce<<<(total + 255) / 256, 256, 0, stream>>>(Cpart, (size_t)M * ldC, SK,
                                                              total, N, scale, bias, Cf, Cb);
        } else {
            k_gemm2<<<grid, 256, 0, stream>>>(A, ldA, B, ldB, K, scale, bias,
                                              Cf, Cb, ldC, nullptr);
        }
    };

    // weight prep (W^T layouts for forward GEMMs)
    k_transpose<<<dim3(32, 512), 256, 0, stream>>>(w0, 16384, 1024, Wtb, 21504, 0);
    k_transpose<<<dim3(32, 128), 256, 0, stream>>>(w1, 4096, 1024, Wtb, 21504, 16384);
    k_transpose<<<dim3(32, 32),  256, 0, stream>>>(w2, 1024, 1024, Wtb, 21504, 20480);
    k_transpose<<<dim3(32, 32),  256, 0, stream>>>(W1, 1024, 1024, W1tb, 1024, 0);
    k_transpose<<<dim3(8, 32),   256, 0, stream>>>(W2, 1024, 256, W2tb, 1024, 0);
    k_convert<<<1024 * 1024 / 1024, 256, 0, stream>>>(W1, W1b, 1024 * 1024 / 4);
    k_convert<<<1024 * 256 / 1024, 256, 0, stream>>>(W2, W2b, 1024 * 256 / 4);

    // features -> P
    k_features<<<2048, 256, 0, stream>>>(t, PG);

    // h = sF * P @ Wt^T  (bf16 out), split-K for occupancy
    gemm(PG, 21504, Wtb, 21504, 2048, 1024, 21504, 8, sF, nullptr, nullptr, h_bf, 1024);

    // Wtb dead -> overwrite with symmetrized straight-layout Wsym (for Gsym = de @ Wsym)
    u16* Wsymb = Wtb;
    k_symmetrize<<<16384, 256, 0, stream>>>(w0, 7, Wsymb);
    k_symmetrize<<<4096, 256, 0, stream>>>(w1, 6, Wsymb + (size_t)16384 * 1024);
    k_symmetrize<<<1024, 256, 0, stream>>>(w2, 5, Wsymb + (size_t)20480 * 1024);

    // MLP forward
    gemm(h_bf, 1024, W1tb, 1024, 2048, 1024, 1024, 4, 1.0f, b1, h1pre, nullptr, 1024);
    k_ln_fwd<<<2048, 256, 0, stream>>>(h1pre, 1024, g1, be1, mu1, r1, a1_bf, nullptr);
    gemm(a1_bf, 1024, W2tb, 1024, 2048, 256, 1024, 8, 1.0f, b2, h2pre, nullptr, 256);
    k_ln_fwd<<<2048, 256, 0, stream>>>(h2pre, 256, g2, be2, mu2, r2, nullptr, xout);

    // backward
    k_ln_bwd<<<2048, 256, 0, stream>>>(nullptr, h2pre, mu2, r2, g2, be2, dh2b, 256);
    gemm(dh2b, 256, W2b, 256, 2048, 1024, 256, 4, 1.0f, nullptr, d_a1, nullptr, 1024);
    k_ln_bwd<<<2048, 256, 0, stream>>>(d_a1, h1pre, mu1, r1, g1, be1, dh1b, 1024);
    gemm(dh1b, 1024, W1b, 1024, 2048, 1024, 1024, 4, sF, nullptr, nullptr, de_bf, 1024);

    // Gsym = de @ Wsym (NT) with fused seg0 contraction; tail (seg1/2) -> Gt
    u16* Gt = PG;   // P dead after GEMM1
    k_gemmG<<<dim3(16, 168), 256, 0, stream>>>(de_bf, 1024, Wsymb, 1024, 1024, t, yout, Gt);

    // y seg1/seg2 from tail
    k_contract_tail<<<2048, 256, 0, stream>>>(Gt, t, yout);
}

// Round 5
// 636.008 us; speedup vs baseline: 1.0457x; 1.0364x over previous
//
#include <hip/hip_runtime.h>
#include <math.h>

typedef unsigned short u16;
typedef __bf16 bf16x8 __attribute__((ext_vector_type(8)));
typedef float f32x4 __attribute__((ext_vector_type(4)));

__device__ __forceinline__ u16 f2bf(float f) {
    unsigned u = __builtin_bit_cast(unsigned, f);
    u += 0x7FFFu + ((u >> 16) & 1u);
    return (u16)(u >> 16);
}
__device__ __forceinline__ float bf2f(u16 h) {
    return __builtin_bit_cast(float, ((unsigned)h) << 16);
}

#define GLOAD_LDS16(g, l)                                                     \
    __builtin_amdgcn_global_load_lds(                                         \
        (const __attribute__((address_space(1))) void*)(g),                   \
        (__attribute__((address_space(3))) void*)(l), 16, 0, 0)

// ---------------------------------------------------------------- converts
__global__ __launch_bounds__(256) void k_convert(const float* __restrict__ in,
                                                 u16* __restrict__ out, int n4) {
    int i = blockIdx.x * 256 + threadIdx.x;
    if (i >= n4) return;
    float4 v = ((const float4*)in)[i];
    union { u16 a[4]; unsigned long long q; } o;
    o.a[0] = f2bf(v.x); o.a[1] = f2bf(v.y); o.a[2] = f2bf(v.z); o.a[3] = f2bf(v.w);
    ((unsigned long long*)out)[i] = o.q;
}

// out[(c)*ldOut + colOff + r] = bf16(in[r*C + c]);  grid = (C/32, R/32)
__global__ __launch_bounds__(256) void k_transpose(const float* __restrict__ in, int R, int C,
                                                   u16* __restrict__ out, int ldOut, int colOff) {
    __shared__ float tile[32][33];
    int tr0 = blockIdx.y * 32;
    int tc0 = blockIdx.x * 32;
    int lr = threadIdx.x >> 5;   // 0..7
    int lc = threadIdx.x & 31;
#pragma unroll
    for (int i = 0; i < 4; i++) {
        int rr = lr + i * 8;
        tile[rr][lc] = in[(size_t)(tr0 + rr) * C + tc0 + lc];
    }
    __syncthreads();
#pragma unroll
    for (int i = 0; i < 4; i++) {
        int rr = lr + i * 8;
        out[(size_t)(tc0 + rr) * ldOut + colOff + tr0 + lc] = f2bf(tile[lc][rr]);
    }
}

// Wsym[u*S+v, :] = bf16(w[u*S+v, :] + w[v*S+u, :]); one block per (u,v), u<=v writes both
__global__ __launch_bounds__(256) void k_symmetrize(const float* __restrict__ w, int lg,
                                                    u16* __restrict__ out) {
    int j = blockIdx.x;
    int S = 1 << lg;
    int u = j >> lg, v = j & (S - 1);
    if (u > v) return;
    int jT = v * S + u;
    int c = threadIdx.x * 4;
    float4 a = *(const float4*)(w + (size_t)j * 1024 + c);
    float4 b = *(const float4*)(w + (size_t)jT * 1024 + c);
    union { u16 h[4]; unsigned long long q; } o;
    o.h[0] = f2bf(a.x + b.x); o.h[1] = f2bf(a.y + b.y);
    o.h[2] = f2bf(a.z + b.z); o.h[3] = f2bf(a.w + b.w);
    *(unsigned long long*)(out + (size_t)j * 1024 + c) = o.q;
    if (jT != j) *(unsigned long long*)(out + (size_t)jT * 1024 + c) = o.q;
}

// ---------------------------------------------------------------- features
__global__ __launch_bounds__(256) void k_features(const float* __restrict__ t,
                                                  u16* __restrict__ P) {
    __shared__ float tr[480];
    int b = blockIdx.x, tid = threadIdx.x;
    for (int i = tid; i < 480; i += 256) tr[i] = t[(size_t)b * 480 + i];
    __syncthreads();
    u16* row = P + (size_t)b * 21504;
    const float s1 = 0.57735026918962576f;
    const float s2 = 0.44721359549995794f;
    for (int k = tid; k < 16384; k += 256) {
        int u = k >> 7, v = k & 127;
        row[k] = f2bf(tr[u] * tr[v]);
    }
    const float* x1 = tr + 128;
    for (int k = tid; k < 4096; k += 256) {
        int u = k >> 6, v = k & 63;
        float s = x1[u*3+0]*x1[v*3+0] + x1[u*3+1]*x1[v*3+1] + x1[u*3+2]*x1[v*3+2];
        row[16384 + k] = f2bf(s * s1);
    }
    const float* x2 = tr + 320;
    for (int k = tid; k < 1024; k += 256) {
        int u = k >> 5, v = k & 31;
        float s = 0.f;
#pragma unroll
        for (int m = 0; m < 5; m++) s += x2[u*5+m] * x2[v*5+m];
        row[20480 + k] = f2bf(s * s2);
    }
}

// ---------------------------------------------------------------- GEMM (NT, BK=64)
// swz==1: 1-D grid 1024 = 8n x 16m x 8sk, decoded so blocks sharing a B-slice
// (and A-slice) have equal blockIdx%8 -> same XCD -> L2-local re-reads.
// Cpart != nullptr -> write fp32 partials (split-K).
__global__ __launch_bounds__(256) void k_gemm2(const u16* __restrict__ A, int ldA,
                                               const u16* __restrict__ B, int ldB,
                                               int kLen, float scale,
                                               const float* __restrict__ bias,
                                               float* __restrict__ Cf,
                                               u16* __restrict__ Cb, int ldC,
                                               float* __restrict__ Cpart, int Mtot,
                                               int swz) {
    __shared__ u16 As[2][128 * 32];
    __shared__ u16 Bs[2][128 * 32];
    const int tid = threadIdx.x;
    const int wave = tid >> 6, lane = tid & 63;
    const int wm = wave >> 1, wn = wave & 1;
    int nT, mT, z;
    if (swz) {
        int L = blockIdx.x;
        z = L & 7;
        int r = L >> 3;
        nT = r >> 4;
        mT = r & 15;
    } else {
        nT = blockIdx.x; mT = blockIdx.y; z = blockIdx.z;
    }
    const int m0 = mT * 128, n0 = nT * 128;
    const size_t kOff = (size_t)z * kLen;

    const u16* aG = A + (size_t)(m0 + wave * 32 + (lane >> 2)) * ldA + kOff + (lane & 3) * 8;
    const u16* bG = B + (size_t)(n0 + wave * 32 + (lane >> 2)) * ldB + kOff + (lane & 3) * 8;
    const size_t aS = (size_t)16 * ldA;
    const size_t bS = (size_t)16 * ldB;
    u16* aL0 = &As[0][(wave * 32) * 32];
    u16* aL1 = &As[0][(wave * 32 + 16) * 32];
    u16* aH0 = &As[1][(wave * 32) * 32];
    u16* aH1 = &As[1][(wave * 32 + 16) * 32];
    u16* bL0 = &Bs[0][(wave * 32) * 32];
    u16* bL1 = &Bs[0][(wave * 32 + 16) * 32];
    u16* bH0 = &Bs[1][(wave * 32) * 32];
    u16* bH1 = &Bs[1][(wave * 32 + 16) * 32];

    f32x4 acc[4][4];
#pragma unroll
    for (int i = 0; i < 4; i++)
#pragma unroll
        for (int j = 0; j < 4; j++) acc[i][j] = (f32x4){0.f, 0.f, 0.f, 0.f};

    const int ml = lane & 15, kq = (lane >> 4) * 8;
    const u16* aRd0 = &As[0][(wm * 64 + ml) * 32 + kq];
    const u16* bRd0 = &Bs[0][(wn * 64 + ml) * 32 + kq];
    const u16* aRd1 = &As[1][(wm * 64 + ml) * 32 + kq];
    const u16* bRd1 = &Bs[1][(wn * 64 + ml) * 32 + kq];

    for (int k = 0; k < kLen; k += 64) {
        GLOAD_LDS16(aG, aL0);
        GLOAD_LDS16(aG + aS, aL1);
        GLOAD_LDS16(aG + 32, aH0);
        GLOAD_LDS16(aG + aS + 32, aH1);
        GLOAD_LDS16(bG, bL0);
        GLOAD_LDS16(bG + bS, bL1);
        GLOAD_LDS16(bG + 32, bH0);
        GLOAD_LDS16(bG + bS + 32, bH1);
        aG += 64; bG += 64;
        __syncthreads();
        {
            bf16x8 af[4], bfv[4];
#pragma unroll
            for (int i = 0; i < 4; i++) af[i]  = *(const bf16x8*)(aRd0 + i * 16 * 32);
#pragma unroll
            for (int j = 0; j < 4; j++) bfv[j] = *(const bf16x8*)(bRd0 + j * 16 * 32);
#pragma unroll
            for (int i = 0; i < 4; i++)
#pragma unroll
                for (int j = 0; j < 4; j++)
                    acc[i][j] = __builtin_amdgcn_mfma_f32_16x16x32_bf16(af[i], bfv[j], acc[i][j], 0, 0, 0);
        }
        {
            bf16x8 af[4], bfv[4];
#pragma unroll
            for (int i = 0; i < 4; i++) af[i]  = *(const bf16x8*)(aRd1 + i * 16 * 32);
#pragma unroll
            for (int j = 0; j < 4; j++) bfv[j] = *(const bf16x8*)(bRd1 + j * 16 * 32);
#pragma unroll
            for (int i = 0; i < 4; i++)
#pragma unroll
                for (int j = 0; j < 4; j++)
                    acc[i][j] = __builtin_amdgcn_mfma_f32_16x16x32_bf16(af[i], bfv[j], acc[i][j], 0, 0, 0);
        }
        __syncthreads();
    }

    const int q = lane >> 4, nl = lane & 15;   // C/D: col=lane&15, row=(lane>>4)*4+reg
    if (Cpart) {
        float* outP = Cpart + (size_t)z * Mtot * ldC;
#pragma unroll
        for (int i = 0; i < 4; i++)
#pragma unroll
            for (int j = 0; j < 4; j++)
#pragma unroll
                for (int reg = 0; reg < 4; reg++) {
                    int row = m0 + wm * 64 + i * 16 + q * 4 + reg;
                    int col = n0 + wn * 64 + j * 16 + nl;
                    outP[(size_t)row * ldC + col] = acc[i][j][reg];
                }
    } else {
#pragma unroll
        for (int i = 0; i < 4; i++)
#pragma unroll
            for (int j = 0; j < 4; j++)
#pragma unroll
                for (int reg = 0; reg < 4; reg++) {
                    int row = m0 + wm * 64 + i * 16 + q * 4 + reg;
                    int col = n0 + wn * 64 + j * 16 + nl;
                    float v = acc[i][j][reg] * scale + (bias ? bias[col] : 0.0f);
                    if (Cf) Cf[(size_t)row * ldC + col] = v;
                    else    Cb[(size_t)row * ldC + col] = f2bf(v);
                }
    }
}

// ---------------------------------------------------------------- GEMM_G (fused)
// 1-D grid 2688 = 168 N-groups x 16 M-members, XCD-swizzled so the 16 blocks
// sharing a Wsym N-tile sit on one XCD (L2-local B re-reads).
// g<128 (seg0): fuse y0[b,g]=sum_v tile*x0[b,v]; g>=128: write bf16 tail to Gt.
__global__ __launch_bounds__(256) void k_gemmG(const u16* __restrict__ A, int ldA,
                                               const u16* __restrict__ B, int ldB,
                                               int kLen,
                                               const float* __restrict__ t,
                                               float* __restrict__ y,
                                               u16* __restrict__ Gt) {
    __shared__ u16 As[2][128 * 32];
    __shared__ u16 Bs[2][128 * 32];
    const int tid = threadIdx.x;
    const int wave = tid >> 6, lane = tid & 63;
    const int wm = wave >> 1, wn = wave & 1;
    int L = blockIdx.x;
    int c = L & 7, r = L >> 3;
    const int bm = r / 21;              // M-tile 0..15
    const int bn = (r % 21) * 8 + c;    // N-group 0..167 (members share blockIdx%8)
    const int m0 = bm * 128, n0 = bn * 128;

    const u16* aG = A + (size_t)(m0 + wave * 32 + (lane >> 2)) * ldA + (lane & 3) * 8;
    const u16* bG = B + (size_t)(n0 + wave * 32 + (lane >> 2)) * ldB + (lane & 3) * 8;
    const size_t aS = (size_t)16 * ldA;
    const size_t bS = (size_t)16 * ldB;
    u16* aL0 = &As[0][(wave * 32) * 32];
    u16* aL1 = &As[0][(wave * 32 + 16) * 32];
    u16* aH0 = &As[1][(wave * 32) * 32];
    u16* aH1 = &As[1][(wave * 32 + 16) * 32];
    u16* bL0 = &Bs[0][(wave * 32) * 32];
    u16* bL1 = &Bs[0][(wave * 32 + 16) * 32];
    u16* bH0 = &Bs[1][(wave * 32) * 32];
    u16* bH1 = &Bs[1][(wave * 32 + 16) * 32];

    f32x4 acc[4][4];
#pragma unroll
    for (int i = 0; i < 4; i++)
#pragma unroll
        for (int j = 0; j < 4; j++) acc[i][j] = (f32x4){0.f, 0.f, 0.f, 0.f};

    const int ml = lane & 15, kq = (lane >> 4) * 8;
    const u16* aRd0 = &As[0][(wm * 64 + ml) * 32 + kq];
    const u16* bRd0 = &Bs[0][(wn * 64 + ml) * 32 + kq];
    const u16* aRd1 = &As[1][(wm * 64 + ml) * 32 + kq];
    const u16* bRd1 = &Bs[1][(wn * 64 + ml) * 32 + kq];

    for (int k = 0; k < kLen; k += 64) {
        GLOAD_LDS16(aG, aL0);
        GLOAD_LDS16(aG + aS, aL1);
        GLOAD_LDS16(aG + 32, aH0);
        GLOAD_LDS16(aG + aS + 32, aH1);
        GLOAD_LDS16(bG, bL0);
        GLOAD_LDS16(bG + bS, bL1);
        GLOAD_LDS16(bG + 32, bH0);
        GLOAD_LDS16(bG + bS + 32, bH1);
        aG += 64; bG += 64;
        __syncthreads();
        {
            bf16x8 af[4], bfv[4];
#pragma unroll
            for (int i = 0; i < 4; i++) af[i]  = *(const bf16x8*)(aRd0 + i * 16 * 32);
#pragma unroll
            for (int j = 0; j < 4; j++) bfv[j] = *(const bf16x8*)(bRd0 + j * 16 * 32);
#pragma unroll
            for (int i = 0; i < 4; i++)
#pragma unroll
                for (int j = 0; j < 4; j++)
                    acc[i][j] = __builtin_amdgcn_mfma_f32_16x16x32_bf16(af[i], bfv[j], acc[i][j], 0, 0, 0);
        }
        {
            bf16x8 af[4], bfv[4];
#pragma unroll
            for (int i = 0; i < 4; i++) af[i]  = *(const bf16x8*)(aRd1 + i * 16 * 32);
#pragma unroll
            for (int j = 0; j < 4; j++) bfv[j] = *(const bf16x8*)(bRd1 + j * 16 * 32);
#pragma unroll
            for (int i = 0; i < 4; i++)
#pragma unroll
                for (int j = 0; j < 4; j++)
                    acc[i][j] = __builtin_amdgcn_mfma_f32_16x16x32_bf16(af[i], bfv[j], acc[i][j], 0, 0, 0);
        }
        __syncthreads();
    }

    const int q = lane >> 4, nl = lane & 15;
    if (bn < 128) {
        // reuse dead As as the cross-wave scratch (keeps LDS at 32 KB)
        float* part = (float*)As;   // [2][128]
#pragma unroll
        for (int i = 0; i < 4; i++)
#pragma unroll
            for (int reg = 0; reg < 4; reg++) {
                int rowL = wm * 64 + i * 16 + q * 4 + reg;
                const float* xr = t + (size_t)(m0 + rowL) * 480 + wn * 64 + nl;
                float s = 0.f;
#pragma unroll
                for (int j = 0; j < 4; j++) s += acc[i][j][reg] * xr[j * 16];
                s += __shfl_xor(s, 1);
                s += __shfl_xor(s, 2);
                s += __shfl_xor(s, 4);
                s += __shfl_xor(s, 8);
                if (nl == 0) part[wn * 128 + rowL] = s;
            }
        __syncthreads();
        if (tid < 128) y[(size_t)(m0 + tid) * 480 + bn] = part[tid] + part[128 + tid];
    } else {
        int c0 = (bn - 128) * 128;
#pragma unroll
        for (int i = 0; i < 4; i++)
#pragma unroll
            for (int j = 0; j < 4; j++)
#pragma unroll
                for (int reg = 0; reg < 4; reg++) {
                    int row = m0 + wm * 64 + i * 16 + q * 4 + reg;
                    int col = c0 + wn * 64 + j * 16 + nl;
                    Gt[(size_t)row * 5120 + col] = f2bf(acc[i][j][reg]);
                }
    }
}

// sum split-K partials + epilogue
__global__ __launch_bounds__(256) void k_reduce(const float* __restrict__ part, size_t stride,
                                                int SK, int total, int N, float scale,
                                                const float* __restrict__ bias,
                                                float* __restrict__ outF, u16* __restrict__ outB) {
    int i = blockIdx.x * 256 + threadIdx.x;
    if (i >= total) return;
    float s = 0.f;
    for (int z = 0; z < SK; z++) s += part[(size_t)z * stride + i];
    float v = s * scale + (bias ? bias[i % N] : 0.0f);
    if (outF) outF[i] = v;
    else      outB[i] = f2bf(v);
}

// ---------------------------------------------------------------- rowwise LN
__device__ __forceinline__ float blockReduce(float v, float* red) {
#pragma unroll
    for (int off = 32; off > 0; off >>= 1) v += __shfl_down(v, off);
    __syncthreads();
    if ((threadIdx.x & 63) == 0) red[threadIdx.x >> 6] = v;
    __syncthreads();
    return red[0] + red[1] + red[2] + red[3];
}

__global__ __launch_bounds__(256) void k_ln_fwd(const float* __restrict__ X, int D,
    const float* __restrict__ g, const float* __restrict__ be,
    float* __restrict__ mu_out, float* __restrict__ r_out,
    u16* __restrict__ a_bf, float* __restrict__ a_f32) {
    __shared__ float red[4];
    int b = blockIdx.x, tid = threadIdx.x;
    const float* x = X + (size_t)b * D;
    int nd = D >> 8;
    float s = 0.f, s2 = 0.f;
    for (int r = 0; r < nd; r++) { float v = x[tid + (r << 8)]; s += v; s2 += v * v; }
    s = blockReduce(s, red);
    s2 = blockReduce(s2, red);
    float mu = s / D;
    float var = s2 / D - mu * mu;
    float rst = rsqrtf(var + 1e-6f);
    if (tid == 0) { mu_out[b] = mu; r_out[b] = rst; }
    for (int r = 0; r < nd; r++) {
        int i = tid + (r << 8);
        float xh = (x[i] - mu) * rst;
        float ln = xh * g[i] + be[i];
        float a = ln / (1.0f + expf(-ln));
        if (a_bf)  a_bf[(size_t)b * D + i] = f2bf(a);
        if (a_f32) a_f32[(size_t)b * D + i] = a;
    }
}

__global__ __launch_bounds__(256) void k_ln_bwd(const float* __restrict__ dup,
    const float* __restrict__ X, const float* __restrict__ mu_in, const float* __restrict__ r_in,
    const float* __restrict__ g, const float* __restrict__ be,
    u16* __restrict__ out_bf, int D) {
    __shared__ float red[4];
    int b = blockIdx.x, tid = threadIdx.x;
    const float* x = X + (size_t)b * D;
    float mu = mu_in[b], rst = r_in[b];
    int nd = D >> 8;
    float w_[4], xh_[4];
    float sw = 0.f, swx = 0.f;
    for (int r = 0; r < nd; r++) {
        int i = tid + (r << 8);
        float xh = (x[i] - mu) * rst;
        float ln = xh * g[i] + be[i];
        float sg = 1.0f / (1.0f + expf(-ln));
        float dsilu = sg * (1.0f + ln * (1.0f - sg));
        float d = dup ? dup[(size_t)b * D + i] : 1.0f;
        float w = g[i] * dsilu * d;
        w_[r] = w; xh_[r] = xh;
        sw += w; swx += w * xh;
    }
    sw = blockReduce(sw, red);
    swx = blockReduce(swx, red);
    float invD = 1.0f / D;
    for (int r = 0; r < nd; r++) {
        int i = tid + (r << 8);
        float dx = rst * (w_[r] - sw * invD - xh_[r] * swx * invD);
        out_bf[(size_t)b * D + i] = f2bf(dx);
    }
}

// ---------------------------------------------------------------- tail contraction
__global__ __launch_bounds__(256) void k_contract_tail(const u16* __restrict__ Gt,
                                                       const float* __restrict__ t,
                                                       float* __restrict__ y) {
    __shared__ float xs[480];
    __shared__ u16 gs[5120];
    int b = blockIdx.x, tid = threadIdx.x;
    for (int i = tid; i < 480; i += 256) xs[i] = t[(size_t)b * 480 + i];
    const uint4* src = (const uint4*)(Gt + (size_t)b * 5120);
    uint4* dst = (uint4*)gs;
    for (int i = tid; i < 640; i += 256) dst[i] = src[i];
    __syncthreads();
    int wave = tid >> 6, lane = tid & 63;
    float* yr = y + (size_t)b * 480;
    const float s1 = 0.57735026918962576f;
    const float s2 = 0.44721359549995794f;
    for (int r = 0; r < 16; r++) {
        int u = wave * 16 + r;
        float gv = bf2f(gs[u * 64 + lane]);
        float a0 = gv * xs[128 + lane * 3 + 0];
        float a1 = gv * xs[128 + lane * 3 + 1];
        float a2 = gv * xs[128 + lane * 3 + 2];
#pragma unroll
        for (int off = 32; off > 0; off >>= 1) {
            a0 += __shfl_down(a0, off);
            a1 += __shfl_down(a1, off);
            a2 += __shfl_down(a2, off);
        }
        if (lane == 0) {
            yr[128 + u * 3 + 0] = a0 * s1;
            yr[128 + u * 3 + 1] = a1 * s1;
            yr[128 + u * 3 + 2] = a2 * s1;
        }
    }
    for (int r = 0; r < 8; r++) {
        int u = wave * 8 + r;
        bool act = lane < 32;
        float gv = act ? bf2f(gs[4096 + u * 32 + lane]) : 0.f;
        float a[5];
#pragma unroll
        for (int m = 0; m < 5; m++)
            a[m] = act ? gv * xs[320 + lane * 5 + m] : 0.f;
#pragma unroll
        for (int off = 32; off > 0; off >>= 1)
#pragma unroll
            for (int m = 0; m < 5; m++) a[m] += __shfl_down(a[m], off);
        if (lane == 0)
#pragma unroll
            for (int m = 0; m < 5; m++) yr[320 + u * 5 + m] = a[m] * s2;
    }
}

// ---------------------------------------------------------------- launch
extern "C" void kernel_launch(void* const* d_in, const int* in_sizes, int n_in,
                              void* d_out, int out_size, void* d_ws, size_t ws_size,
                              hipStream_t stream) {
    const float* t   = (const float*)d_in[0];
    const float* w0  = (const float*)d_in[1];
    const float* w1  = (const float*)d_in[2];
    const float* w2  = (const float*)d_in[3];
    const float* W1  = (const float*)d_in[4];
    const float* b1  = (const float*)d_in[5];
    const float* g1  = (const float*)d_in[6];
    const float* be1 = (const float*)d_in[7];
    const float* W2  = (const float*)d_in[8];
    const float* b2  = (const float*)d_in[9];
    const float* g2  = (const float*)d_in[10];
    const float* be2 = (const float*)d_in[11];

    float* xout = (float*)d_out;                    // 2048*256
    float* yout = xout + (size_t)2048 * 256;        // 2048*480

    char* ws = (char*)d_ws;
    size_t off = 0;
    auto alloc = [&](size_t bytes) -> void* {
        void* p = ws + off;
        off += (bytes + 255) & ~(size_t)255;
        return p;
    };
    u16*   PG    = (u16*)alloc((size_t)2048 * 21504 * 2);  // P, later Gt tail (aliased)
    u16*   Wtb   = (u16*)alloc((size_t)1024 * 21504 * 2);  // W^T bf16; later Wsym (aliased)
    u16*   W1b   = (u16*)alloc((size_t)1024 * 1024 * 2);
    u16*   W1tb  = (u16*)alloc((size_t)1024 * 1024 * 2);
    u16*   W2b   = (u16*)alloc((size_t)1024 * 256 * 2);
    u16*   W2tb  = (u16*)alloc((size_t)256 * 1024 * 2);
    u16*   h_bf  = (u16*)alloc((size_t)2048 * 1024 * 2);
    float* h1pre = (float*)alloc((size_t)2048 * 1024 * 4);
    float* mu1   = (float*)alloc(2048 * 4);
    float* r1    = (float*)alloc(2048 * 4);
    u16*   a1_bf = (u16*)alloc((size_t)2048 * 1024 * 2);
    float* h2pre = (float*)alloc((size_t)2048 * 256 * 4);
    float* mu2   = (float*)alloc(2048 * 4);
    float* r2    = (float*)alloc(2048 * 4);
    u16*   dh2b  = (u16*)alloc((size_t)2048 * 256 * 2);
    float* d_a1  = (float*)alloc((size_t)2048 * 1024 * 4);
    u16*   dh1b  = (u16*)alloc((size_t)2048 * 1024 * 2);
    u16*   de_bf = (u16*)alloc((size_t)2048 * 1024 * 2);
    float* Cpart = (float*)(ws + off);
    size_t cpartBytes = (ws_size > off) ? (ws_size - off) : 0;
    (void)in_sizes; (void)n_in; (void)out_size;

    const float sF = 1.0f / sqrtf(21504.0f);

    // generic GEMM helper (small GEMMs): 3-D grid, optional split-K
    auto gemm = [&](const u16* A, int ldA, const u16* B, int ldB, int M, int N, int K,
                    int SKwant, float scale, const float* bias,
                    float* Cf, u16* Cb, int ldC) {
        int SK = SKwant;
        size_t slice = (size_t)M * ldC * 4;
        if (SK > 1 && cpartBytes < 2 * slice) SK = 1;
        if (SK > 1 && (size_t)SK * slice > cpartBytes) SK = (int)(cpartBytes / slice);
        while (SK > 1 && !((K % SK) == 0 && ((K / SK) % 64) == 0)) SK--;
        dim3 grid(N / 128, M / 128, SK);
        if (SK > 1) {
            k_gemm2<<<grid, 256, 0, stream>>>(A, ldA, B, ldB, K / SK, 0.f, nullptr,
                                              nullptr, nullptr, ldC, Cpart, M, 0);
            int total = M * ldC;
            k_reduce<<<(total + 255) / 256, 256, 0, stream>>>(Cpart, (size_t)M * ldC, SK,
                                                              total, N, scale, bias, Cf, Cb);
        } else {
            k_gemm2<<<grid, 256, 0, stream>>>(A, ldA, B, ldB, K, scale, bias,
                                              Cf, Cb, ldC, nullptr, M, 0);
        }
    };

    // weight prep (W^T layouts for forward GEMMs)
    k_transpose<<<dim3(32, 512), 256, 0, stream>>>(w0, 16384, 1024, Wtb, 21504, 0);
    k_transpose<<<dim3(32, 128), 256, 0, stream>>>(w1, 4096, 1024, Wtb, 21504, 16384);
    k_transpose<<<dim3(32, 32),  256, 0, stream>>>(w2, 1024, 1024, Wtb, 21504, 20480);
    k_transpose<<<dim3(32, 32),  256, 0, stream>>>(W1, 1024, 1024, W1tb, 1024, 0);
    k_transpose<<<dim3(8, 32),   256, 0, stream>>>(W2, 1024, 256, W2tb, 1024, 0);
    k_convert<<<1024 * 1024 / 1024, 256, 0, stream>>>(W1, W1b, 1024 * 1024 / 4);
    k_convert<<<1024 * 256 / 1024, 256, 0, stream>>>(W2, W2b, 1024 * 256 / 4);

    // features -> P
    k_features<<<2048, 256, 0, stream>>>(t, PG);

    // h = sF * P @ Wt^T: SK=8, XCD-swizzled 1-D launch (sk -> XCD; B-slice L2-local)
    k_gemm2<<<dim3(1024), 256, 0, stream>>>(PG, 21504, Wtb, 21504, 21504 / 8, 0.f, nullptr,
                                            nullptr, nullptr, 1024, Cpart, 2048, 1);
    {
        int total = 2048 * 1024;
        k_reduce<<<(total + 255) / 256, 256, 0, stream>>>(Cpart, (size_t)2048 * 1024, 8,
                                                          total, 1024, sF, nullptr,
                                                          nullptr, h_bf);
    }

    // Wtb dead -> overwrite with symmetrized straight-layout Wsym (for Gsym = de @ Wsym)
    u16* Wsymb = Wtb;
    k_symmetrize<<<16384, 256, 0, stream>>>(w0, 7, Wsymb);
    k_symmetrize<<<4096, 256, 0, stream>>>(w1, 6, Wsymb + (size_t)16384 * 1024);
    k_symmetrize<<<1024, 256, 0, stream>>>(w2, 5, Wsymb + (size_t)20480 * 1024);

    // MLP forward
    gemm(h_bf, 1024, W1tb, 1024, 2048, 1024, 1024, 4, 1.0f, b1, h1pre, nullptr, 1024);
    k_ln_fwd<<<2048, 256, 0, stream>>>(h1pre, 1024, g1, be1, mu1, r1, a1_bf, nullptr);
    gemm(a1_bf, 1024, W2tb, 1024, 2048, 256, 1024, 8, 1.0f, b2, h2pre, nullptr, 256);
    k_ln_fwd<<<2048, 256, 0, stream>>>(h2pre, 256, g2, be2, mu2, r2, nullptr, xout);

    // backward
    k_ln_bwd<<<2048, 256, 0, stream>>>(nullptr, h2pre, mu2, r2, g2, be2, dh2b, 256);
    gemm(dh2b, 256, W2b, 256, 2048, 1024, 256, 4, 1.0f, nullptr, d_a1, nullptr, 1024);
    k_ln_bwd<<<2048, 256, 0, stream>>>(d_a1, h1pre, mu1, r1, g1, be1, dh1b, 1024);
    gemm(dh1b, 1024, W1b, 1024, 2048, 1024, 1024, 4, sF, nullptr, nullptr, de_bf, 1024);

    // Gsym = de @ Wsym (NT), XCD-swizzled; fused seg0 contraction; tail -> Gt
    u16* Gt = PG;   // P dead after GEMM1
    k_gemmG<<<dim3(2688), 256, 0, stream>>>(de_bf, 1024, Wsymb, 1024, 1024, t, yout, Gt);

    // y seg1/seg2 from tail
    k_contract_tail<<<2048, 256, 0, stream>>>(Gt, t, yout);
}